// Round 13
// baseline (630.110 us; speedup 1.0000x reference)
//
#include <hip/hip_runtime.h>
#include <math.h>

#define NNODES 50000
#define DIM 128
#define DEDGE 64

typedef __attribute__((ext_vector_type(8))) short bf16x8;
typedef __attribute__((ext_vector_type(4))) float f32x4;
typedef __attribute__((ext_vector_type(2))) float f32x2;

__device__ __forceinline__ float bf_lo(unsigned u) { return __builtin_bit_cast(float, u << 16); }
__device__ __forceinline__ float bf_hi(unsigned u) { return __builtin_bit_cast(float, u & 0xFFFF0000u); }
__device__ __forceinline__ float bf_s(short s) {
    return __builtin_bit_cast(float, ((unsigned)(unsigned short)s) << 16);
}
__device__ __forceinline__ unsigned short f2b_rtn(float f) {
    unsigned u = __builtin_bit_cast(unsigned, f);
    u += 0x7FFFu + ((u >> 16) & 1u);
    return (unsigned short)(u >> 16);
}

// ---------------------------------------------------------------------------
// edge_index dtype detection (int64 per reference vs int32 per harness doc)
// ---------------------------------------------------------------------------
__global__ void detect_mode_kernel(const void* __restrict__ ei, int* __restrict__ flag) {
    __shared__ int bad;
    if (threadIdx.x == 0) bad = 0;
    __syncthreads();
    const long long* p = (const long long*)ei;
    int localbad = 0;
    for (int i = threadIdx.x; i < 4096; i += blockDim.x) {
        long long v = p[i];
        if (v < 0 || v >= NNODES) localbad = 1;
    }
    if (localbad) atomicOr(&bad, 1);
    __syncthreads();
    if (threadIdx.x == 0) *flag = bad ? 0 : 1;   // 1 = int64 mode
}

__device__ __forceinline__ int load_idx(const void* ei, long long pos, int mode64) {
    if (mode64) return (int)((const long long*)ei)[pos];
    return ((const int*)ei)[pos];
}

// ---------------------------------------------------------------------------
// prep: weights -> FRAGMENT-ORDER single-bf16 tables; (1+eps) folded exactly
// into the h-half (k>=128) of the GIN weights.
// layout (shorts): aW0@0 aW1@8192 mW0@16384 mW1@49152 lpW1@81920  (98304 total)
// ---------------------------------------------------------------------------
__global__ void prep_weights(const float* __restrict__ aW0, const float* __restrict__ aW1,
                             const float* __restrict__ mW0, const float* __restrict__ mW1,
                             const float* __restrict__ lpW1,
                             const float* __restrict__ eps0p, const float* __restrict__ eps1p,
                             short* __restrict__ wt)
{
    int i = blockIdx.x * 256 + threadIdx.x;   // 0..98303 (384 blocks)
    const float* src; int K, off, f;
    float scale_hi = 1.0f;   // applied to k>=128 rows (GIN h-half)
    if (i < 8192)        { src = aW0;  K = 64;  off = 0;     f = i; }
    else if (i < 16384)  { src = aW1;  K = 64;  off = 8192;  f = i - 8192; }
    else if (i < 49152)  { src = mW0;  K = 256; off = 16384; f = i - 16384;
                           scale_hi = 1.0f + eps0p[0]; }
    else if (i < 81920)  { src = mW1;  K = 256; off = 49152; f = i - 49152;
                           scale_hi = 1.0f + eps1p[0]; }
    else                 { src = lpW1; K = 128; off = 81920; f = i - 81920; }
    const int NKC = K >> 5;
    int j = f & 7, l = (f >> 3) & 63, c = f >> 9;
    int kc = c % NKC, n = c / NKC;
    int col = n * 16 + (l & 15);
    int k = kc * 32 + ((l >> 4) << 3) + j;
    float v = src[k * DIM + col];
    if (k >= 128) v *= scale_hi;
    wt[off + f] = (short)f2b_rtn(v);
}

// f32 -> bf16 table conversion (coalesced, 8 elems/thread)
__global__ void f32_to_bf16_kernel(const float* __restrict__ in,
                                   unsigned short* __restrict__ out, long long n)
{
    long long i = ((long long)blockIdx.x * 256 + threadIdx.x) * 8;
    if (i >= n) return;
    f32x4 a = *(const f32x4*)(in + i);
    f32x4 b = *(const f32x4*)(in + i + 4);
    unsigned short v[8];
#pragma unroll
    for (int t = 0; t < 4; t++) { v[t] = f2b_rtn(a[t]); v[4 + t] = f2b_rtn(b[t]); }
    unsigned p0 = v[0] | ((unsigned)v[1] << 16);
    unsigned p1 = v[2] | ((unsigned)v[3] << 16);
    unsigned p2 = v[4] | ((unsigned)v[5] << 16);
    unsigned p3 = v[6] | ((unsigned)v[7] << 16);
    f32x4 pk = {__builtin_bit_cast(float, p0), __builtin_bit_cast(float, p1),
                __builtin_bit_cast(float, p2), __builtin_bit_cast(float, p3)};
    *(f32x4*)(out + i) = pk;
}

// ---------------------------------------------------------------------------
// CSR build: histogram of dst; fast 3-pass exclusive scan; scatter.
// ---------------------------------------------------------------------------
__global__ void hist_kernel(const void* __restrict__ ei, const int* __restrict__ modep,
                            int* __restrict__ counts, int E)
{
    const int mode64 = *modep;
    for (int e = blockIdx.x * 256 + threadIdx.x; e < E; e += gridDim.x * 256)
        atomicAdd(&counts[load_idx(ei, (long long)E + e, mode64)], 1);
}

__global__ __launch_bounds__(1024) void scan1_kernel(const int* __restrict__ counts,
                                                     int* __restrict__ cursor,
                                                     int* __restrict__ bsums)
{
    __shared__ int part[1024];
    const int t = threadIdx.x;
    const int i = blockIdx.x * 1024 + t;
    int v = (i < NNODES) ? counts[i] : 0;
    part[t] = v;
    __syncthreads();
    for (int d = 1; d < 1024; d <<= 1) {
        int u = (t >= d) ? part[t - d] : 0;
        __syncthreads();
        part[t] += u;
        __syncthreads();
    }
    if (i < NNODES) cursor[i] = part[t] - v;   // exclusive within block
    if (t == 1023) bsums[blockIdx.x] = part[1023];
}

__global__ void scan2_kernel(int* __restrict__ bsums, int nb)
{
    if (threadIdx.x == 0 && blockIdx.x == 0) {
        int run = 0;
        for (int b = 0; b < nb; b++) { int c = bsums[b]; bsums[b] = run; run += c; }
    }
}

__global__ __launch_bounds__(1024) void scan3_kernel(int* __restrict__ cursor,
                                                     const int* __restrict__ bsums)
{
    const int i = blockIdx.x * 1024 + threadIdx.x;
    if (i < NNODES) cursor[i] += bsums[blockIdx.x];
}

__global__ void scatter_kernel(const void* __restrict__ ei, const int* __restrict__ modep,
                               int* __restrict__ cursor, int* __restrict__ perm,
                               int* __restrict__ srcs, int* __restrict__ dsts, int E)
{
    const int mode64 = *modep;
    for (int e = blockIdx.x * 256 + threadIdx.x; e < E; e += gridDim.x * 256) {
        int d = load_idx(ei, (long long)E + e, mode64);
        int s = load_idx(ei, e, mode64);
        int pos = atomicAdd(&cursor[d], 1);
        perm[pos] = e;
        srcs[pos] = s;
        dsts[pos] = d;
    }
}

// ---------------------------------------------------------------------------
// eattr -> bf16, permuted into dst-sorted order (linear reads downstream)
// ---------------------------------------------------------------------------
__global__ void eattr_sort_bf16(const float* __restrict__ eattr, const int* __restrict__ perm,
                                unsigned short* __restrict__ out, int E)
{
    long long i = ((long long)blockIdx.x * 256 + threadIdx.x) * 8;
    if (i >= (long long)E * DEDGE) return;
    long long pos = i >> 6;
    int k = (int)(i & 63);
    long long eid = perm[pos];
    f32x4 a = *(const f32x4*)(eattr + eid * DEDGE + k);
    f32x4 b = *(const f32x4*)(eattr + eid * DEDGE + k + 4);
    unsigned short v[8];
#pragma unroll
    for (int t = 0; t < 4; t++) { v[t] = f2b_rtn(a[t]); v[4 + t] = f2b_rtn(b[t]); }
    unsigned p0 = v[0] | ((unsigned)v[1] << 16);
    unsigned p1 = v[2] | ((unsigned)v[3] << 16);
    unsigned p2 = v[4] | ((unsigned)v[5] << 16);
    unsigned p3 = v[6] | ((unsigned)v[7] << 16);
    f32x4 pk = {__builtin_bit_cast(float, p0), __builtin_bit_cast(float, p1),
                __builtin_bit_cast(float, p2), __builtin_bit_cast(float, p3)};
    __builtin_nontemporal_store(pk, (f32x4*)(out + i));
}

// ---------------------------------------------------------------------------
// edge message + scatter over dst-SORTED edges, 2 sub-tiles (32 edges) / wave:
//   agg[dst] += relu(h[src] + eattr@W + b)
// LDS buffer reused across sub-tiles; segmented sum carried across the
// boundary; scalar atomics only at run boundaries.
// ---------------------------------------------------------------------------
__global__ __launch_bounds__(256, 4) void edge_msg_sorted(
    const unsigned short* __restrict__ hb, const unsigned short* __restrict__ eattrs,
    const int* __restrict__ srcs, const int* __restrict__ dsts,
    const short* __restrict__ Wb,
    const float* __restrict__ bvec, float* __restrict__ agg, int E)
{
    __shared__ float e_lds[4][16][132];
    const int lane = threadIdx.x & 63;
    const int w = threadIdx.x >> 6;
    const int lg = lane >> 4, lr = lane & 15;
    const long long p0 = ((long long)blockIdx.x * 4 + w) * 32;
    if (p0 >= E) return;

    float bias[8];
#pragma unroll
    for (int n = 0; n < 8; n++) bias[n] = bvec[n * 16 + lr];

    float a0 = 0.f, a1 = 0.f;
    int prev = -1;
    const bool fullwave = (p0 + 32 <= E);

#pragma unroll
    for (int st = 0; st < 2; st++) {
        const long long t0 = p0 + st * 16;
        if (t0 >= E) break;
        const long long pos = (t0 + lr < E) ? (t0 + lr) : (E - 1);
        const int sidx = srcs[pos];
        const int didx = dsts[pos];

        f32x4 acc[8];
#pragma unroll
        for (int n = 0; n < 8; n++) {
            float b = bias[n];
            acc[n] = (f32x4){b, b, b, b};
        }
        bf16x8 a[2];
#pragma unroll
        for (int kc = 0; kc < 2; kc++)
            a[kc] = __builtin_nontemporal_load(
                (const bf16x8*)(eattrs + pos * DEDGE + kc * 32 + lg * 8));

#pragma unroll
        for (int n = 0; n < 8; n++) {
#pragma unroll
            for (int kc = 0; kc < 2; kc++) {
                bf16x8 bh = *(const bf16x8*)(Wb + ((n * 2 + kc) * 64 + lane) * 8);
                acc[n] = __builtin_amdgcn_mfma_f32_16x16x32_bf16(a[kc], bh, acc[n], 0, 0, 0);
            }
        }
        // D layout: col = n*16+lr, row = lg*4+r
#pragma unroll
        for (int n = 0; n < 8; n++)
#pragma unroll
            for (int r = 0; r < 4; r++)
                e_lds[w][lg * 4 + r][n * 16 + lr] = acc[n][r];

        if (fullwave) {
            unsigned gu[16];
            int dvs[16];
#pragma unroll
            for (int r = 0; r < 16; r++) {
                int si = __shfl(sidx, r);
                gu[r] = *(const unsigned*)&hb[(long long)si * DIM + 2 * lane];
            }
#pragma unroll
            for (int r = 0; r < 16; r++) dvs[r] = __shfl(didx, r);
#pragma unroll
            for (int r = 0; r < 16; r++) {
                f32x2 ev = *(const f32x2*)&e_lds[w][r][2 * lane];
                float m0 = fmaxf(ev.x + bf_lo(gu[r]), 0.f);
                float m1 = fmaxf(ev.y + bf_hi(gu[r]), 0.f);
                if (dvs[r] != prev && prev >= 0) {
                    float* d = &agg[(long long)prev * DIM + 2 * lane];
                    unsafeAtomicAdd(d, a0);
                    unsafeAtomicAdd(d + 1, a1);
                    a0 = 0.f; a1 = 0.f;
                }
                a0 += m0; a1 += m1; prev = dvs[r];
            }
        } else {
            for (int r = 0; r < 16; r++) {
                if (t0 + r >= E) break;
                int di = __shfl(didx, r);
                int si = __shfl(sidx, r);
                f32x2 ev = *(const f32x2*)&e_lds[w][r][2 * lane];
                unsigned u = *(const unsigned*)&hb[(long long)si * DIM + 2 * lane];
                float m0 = fmaxf(ev.x + bf_lo(u), 0.f);
                float m1 = fmaxf(ev.y + bf_hi(u), 0.f);
                if (di != prev && prev >= 0) {
                    float* d = &agg[(long long)prev * DIM + 2 * lane];
                    unsafeAtomicAdd(d, a0);
                    unsafeAtomicAdd(d + 1, a1);
                    a0 = 0.f; a1 = 0.f;
                }
                a0 += m0; a1 += m1; prev = di;
            }
        }
    }
    if (prev >= 0) {
        float* d = &agg[(long long)prev * DIM + 2 * lane];
        unsafeAtomicAdd(d, a0);
        unsafeAtomicAdd(d + 1, a1);
    }
}

// ---------------------------------------------------------------------------
// GIN update: houtb = bf16(act([agg | (1+eps)*h] @ W + b)); eps pre-folded.
// agg streamed non-temporally (one-shot), h already bf16. 64 MFMA.
// ---------------------------------------------------------------------------
__global__ __launch_bounds__(256, 4) void node_update_mfma(
    const float* __restrict__ agg, const unsigned short* __restrict__ hb,
    const short* __restrict__ Wb, const float* __restrict__ bvec,
    unsigned short* __restrict__ houtb, int relu_flag)
{
    __shared__ float st[4][16][132];
    const int lane = threadIdx.x & 63;
    const int w = threadIdx.x >> 6;
    const int lg = lane >> 4, lr = lane & 15;
    const int n0 = (blockIdx.x * 4 + w) * 16;
    if (n0 >= NNODES) return;
    const int arow = (n0 + lr < NNODES) ? (n0 + lr) : (NNODES - 1);

    f32x4 acc[8];
#pragma unroll
    for (int n = 0; n < 8; n++) {
        float b = bvec[n * 16 + lr];
        acc[n] = (f32x4){b, b, b, b};
    }
#pragma unroll
    for (int kc = 0; kc < 8; kc++) {
        bf16x8 av;
        if (kc < 4) {
            const int k = kc * 32 + lg * 8;
            f32x4 v0 = __builtin_nontemporal_load((const f32x4*)(agg + (long long)arow * DIM + k));
            f32x4 v1 = __builtin_nontemporal_load((const f32x4*)(agg + (long long)arow * DIM + k + 4));
#pragma unroll
            for (int i = 0; i < 4; i++) {
                av[i] = (short)f2b_rtn(v0[i]);
                av[4 + i] = (short)f2b_rtn(v1[i]);
            }
        } else {
            av = *(const bf16x8*)(hb + (long long)arow * DIM + (kc - 4) * 32 + lg * 8);
        }
#pragma unroll
        for (int n = 0; n < 8; n++) {
            bf16x8 bh = *(const bf16x8*)(Wb + ((n * 8 + kc) * 64 + lane) * 8);
            acc[n] = __builtin_amdgcn_mfma_f32_16x16x32_bf16(av, bh, acc[n], 0, 0, 0);
        }
    }
#pragma unroll
    for (int n = 0; n < 8; n++) {
#pragma unroll
        for (int r = 0; r < 4; r++) {
            float z = acc[n][r];
            z = relu_flag ? fmaxf(z, 0.f) : (z > 0.f ? z : 0.2f * z);
            st[w][lg * 4 + r][n * 16 + lr] = z;
        }
    }
    for (int r = 0; r < 16; r++) {
        int row = n0 + r;
        if (row >= NNODES) break;
        f32x2 v = *(const f32x2*)&st[w][r][2 * lane];
        unsigned pk = (unsigned)f2b_rtn(v.x) | ((unsigned)f2b_rtn(v.y) << 16);
        *(unsigned*)&houtb[(long long)row * DIM + 2 * lane] = pk;
    }
}

// ---------------------------------------------------------------------------
// he writer (pure stream): out_he[e] = h[src[e]]*h[dst[e]] (exact f32 product
// of bf16). Per instruction the wave covers TWO full rows densely:
// lane l -> row e0+2t+(l>>5), floats [(l&31)*4, +4) -> 64x16B = 1KB stores.
// ---------------------------------------------------------------------------
__global__ __launch_bounds__(256) void he_write_kernel(
    const unsigned short* __restrict__ hb, const void* __restrict__ ei,
    const int* __restrict__ modep, float* __restrict__ out_he, int E)
{
    const int mode64 = *modep;
    const int lane = threadIdx.x & 63;
    const int w = threadIdx.x >> 6;
    const int half = lane >> 5;          // 0/1: which of the 2 rows
    const int col4 = (lane & 31) * 4;    // float offset within row
    const long long nw = (long long)gridDim.x * 4;

    for (long long e0 = ((long long)blockIdx.x * 4 + w) * 8; e0 < E; e0 += nw * 8) {
#pragma unroll
        for (int t = 0; t < 4; t++) {
            long long e = e0 + 2 * t + half;
            if (e >= E) break;
            int si = load_idx(ei, e, mode64);
            int di = load_idx(ei, (long long)E + e, mode64);
            unsigned s0 = *(const unsigned*)&hb[(long long)si * DIM + col4];
            unsigned s1 = *(const unsigned*)&hb[(long long)si * DIM + col4 + 2];
            unsigned d0 = *(const unsigned*)&hb[(long long)di * DIM + col4];
            unsigned d1 = *(const unsigned*)&hb[(long long)di * DIM + col4 + 2];
            f32x4 p = { bf_lo(s0) * bf_lo(d0), bf_hi(s0) * bf_hi(d0),
                        bf_lo(s1) * bf_lo(d1), bf_hi(s1) * bf_hi(d1) };
            __builtin_nontemporal_store(p, (f32x4*)(out_he + e * DIM + col4));
        }
    }
}

// ---------------------------------------------------------------------------
// edge head (no he stores — he_write_kernel owns that stream):
// gather hb rows, z = leaky((hs*hd)@W1+b1), 32 MFMA; yhat = softmax2,
// coalesced 128B store/tile. 1 tile/wave, 6 waves/SIMD (measured optimum;
// 8 waves thrashes L2/WC [r11], 2 tiles/wave regresses [r10]).
// ---------------------------------------------------------------------------
__global__ __launch_bounds__(256, 6) void edge_head_mfma(
    const unsigned short* __restrict__ hb, const void* __restrict__ ei,
    const int* __restrict__ modep,
    const short* __restrict__ W1b, const float* __restrict__ b1,
    const float* __restrict__ W2, const float* __restrict__ b2,
    float* __restrict__ out_y, int E)
{
    const int mode64 = *modep;
    const int lane = threadIdx.x & 63;
    const int w = threadIdx.x >> 6;
    const int lg = lane >> 4, lr = lane & 15;
    const long long e0 = ((long long)blockIdx.x * 4 + w) * 16;
    if (e0 >= E) return;
    const bool full = (e0 + 16 <= E);
    const long long erow = (full || e0 + lr < E) ? (e0 + lr) : (E - 1);
    int si = load_idx(ei, erow, mode64);
    int di = load_idx(ei, (long long)E + erow, mode64);

    f32x4 acc[8];
#pragma unroll
    for (int n = 0; n < 8; n++) {
        float b = b1[n * 16 + lr];
        acc[n] = (f32x4){b, b, b, b};
    }
    bf16x8 ab[4];
#pragma unroll
    for (int kc = 0; kc < 4; kc++) {
        const int k = kc * 32 + lg * 8;
        bf16x8 hs = *(const bf16x8*)(hb + (long long)si * DIM + k);
        bf16x8 hd = *(const bf16x8*)(hb + (long long)di * DIM + k);
#pragma unroll
        for (int i = 0; i < 8; i++)
            ab[kc][i] = (short)f2b_rtn(bf_s(hs[i]) * bf_s(hd[i]));
    }
#pragma unroll
    for (int n = 0; n < 8; n++) {
#pragma unroll
        for (int kc = 0; kc < 4; kc++) {
            bf16x8 bh = *(const bf16x8*)(W1b + ((n * 4 + kc) * 64 + lane) * 8);
            acc[n] = __builtin_amdgcn_mfma_f32_16x16x32_bf16(ab[kc], bh, acc[n], 0, 0, 0);
        }
    }
    float q0[4] = {0.f, 0.f, 0.f, 0.f}, q1[4] = {0.f, 0.f, 0.f, 0.f};
#pragma unroll
    for (int n = 0; n < 8; n++) {
        float w2a = W2[(n * 16 + lr) * 2 + 0];
        float w2b = W2[(n * 16 + lr) * 2 + 1];
#pragma unroll
        for (int r = 0; r < 4; r++) {
            float z = acc[n][r];
            z = z > 0.f ? z : 0.2f * z;
            q0[r] = fmaf(z, w2a, q0[r]);
            q1[r] = fmaf(z, w2b, q1[r]);
        }
    }
#pragma unroll
    for (int m = 1; m < 16; m <<= 1) {
#pragma unroll
        for (int r = 0; r < 4; r++) {
            q0[r] += __shfl_xor(q0[r], m);
            q1[r] += __shfl_xor(q1[r], m);
        }
    }
    float c0 = b2[0], c1 = b2[1];
    float s0[4], s1[4];
#pragma unroll
    for (int r = 0; r < 4; r++) {
        float l0 = q0[r] + c0, l1 = q1[r] + c1;
        float mx = fmaxf(l0, l1);
        float x0 = expf(l0 - mx), x1 = expf(l1 - mx);
        float inv = 1.f / (x0 + x1);
        s0[r] = x0 * inv;
        s1[r] = x1 * inv;
    }
    if (full) {
        float ea = (lane & 2) ? s0[1] : s0[0];
        float eb = (lane & 2) ? s0[3] : s0[2];
        float ec = (lane & 2) ? s1[1] : s1[0];
        float ed = (lane & 2) ? s1[3] : s1[2];
        float e0v = (lane & 4) ? eb : ea;
        float e1v = (lane & 4) ? ed : ec;
        float ex = (lane & 1) ? e1v : e0v;
        float v = __shfl(ex, ((lane >> 3) << 4) + (lane & 7));
        if (lane < 32)
            __builtin_nontemporal_store(v, &out_y[e0 * 2 + lane]);
    } else if (lr == 0) {
#pragma unroll
        for (int r = 0; r < 4; r++) {
            long long e = e0 + lg * 4 + r;
            if (e < E) {
                out_y[e * 2 + 0] = s0[r];
                out_y[e * 2 + 1] = s1[r];
            }
        }
    }
}

extern "C" void kernel_launch(void* const* d_in, const int* in_sizes, int n_in,
                              void* d_out, int out_size, void* d_ws, size_t ws_size,
                              hipStream_t stream)
{
    const float* x     = (const float*)d_in[0];
    const void*  ei    = d_in[1];
    const float* eattr = (const float*)d_in[2];
    const float* aW0   = (const float*)d_in[3];
    const float* ab0   = (const float*)d_in[4];
    const float* mW0   = (const float*)d_in[5];
    const float* mb0   = (const float*)d_in[6];
    const float* eps0  = (const float*)d_in[7];
    const float* aW1   = (const float*)d_in[8];
    const float* ab1   = (const float*)d_in[9];
    const float* mW1   = (const float*)d_in[10];
    const float* mb1   = (const float*)d_in[11];
    const float* eps1  = (const float*)d_in[12];
    const float* lpW1  = (const float*)d_in[13];
    const float* lpb1  = (const float*)d_in[14];
    const float* lpW2  = (const float*)d_in[15];
    const float* lpb2  = (const float*)d_in[16];

    const int E = in_sizes[1] / 2;
    const long long NTAB = (long long)NNODES * DIM;   // 6.4M

    float* wsf  = (float*)d_ws;
    int*   flag = (int*)d_ws;
    float* agg  = wsf + 64;
    short* wt   = (short*)(agg + NTAB);
    unsigned short* xb_h2b = (unsigned short*)(wt + 98304); // x bf16, later h2 bf16
    unsigned short* h1b    = xb_h2b + NTAB;
    int* counts = (int*)(h1b + NTAB);
    int* cursor = counts + 50048;
    int* bsums  = cursor + 50048;            // 64 used
    int* perm   = bsums + 64;
    int* srcs   = perm + E;
    int* dsts   = srcs + E;
    unsigned short* eattrs = (unsigned short*)(dsts + E);  // sorted bf16 eattr

    float* out_he = (float*)d_out;
    float* out_y  = out_he + (long long)E * DIM;

    const short* aW0b  = wt;
    const short* aW1b  = wt + 8192;
    const short* mW0b  = wt + 16384;
    const short* mW1b  = wt + 49152;
    const short* lpW1b = wt + 81920;

    detect_mode_kernel<<<1, 256, 0, stream>>>(ei, flag);
    prep_weights<<<384, 256, 0, stream>>>(aW0, aW1, mW0, mW1, lpW1, eps0, eps1, wt);
    f32_to_bf16_kernel<<<(int)(NTAB / 8 / 256), 256, 0, stream>>>(x, xb_h2b, NTAB);

    // ---- CSR build (edge structure is layer-invariant) ----
    hipMemsetAsync(counts, 0, 50048 * sizeof(int), stream);
    hist_kernel<<<1024, 256, 0, stream>>>(ei, flag, counts, E);
    const int sblocks = (NNODES + 1023) / 1024;   // 49
    scan1_kernel<<<sblocks, 1024, 0, stream>>>(counts, cursor, bsums);
    scan2_kernel<<<1, 64, 0, stream>>>(bsums, sblocks);
    scan3_kernel<<<sblocks, 1024, 0, stream>>>(cursor, bsums);
    scatter_kernel<<<1024, 256, 0, stream>>>(ei, flag, cursor, perm, srcs, dsts, E);
    eattr_sort_bf16<<<(E * DEDGE / 8 + 255) / 256, 256, 0, stream>>>(eattr, perm, eattrs, E);

    const int eblocks32 = (E + 127) / 128;   // 32 edges per wave, 4 waves/block
    const int eblocks16 = (E + 63) / 64;     // 16 edges per wave
    const int nblocks = (NNODES + 63) / 64;

    // ---- layer 0 ----
    hipMemsetAsync(agg, 0, NTAB * sizeof(float), stream);
    edge_msg_sorted<<<eblocks32, 256, 0, stream>>>(xb_h2b, eattrs, srcs, dsts,
                                                   aW0b, ab0, agg, E);
    node_update_mfma<<<nblocks, 256, 0, stream>>>(agg, xb_h2b, mW0b, mb0, h1b, 0);

    // ---- layer 1 ----
    hipMemsetAsync(agg, 0, NTAB * sizeof(float), stream);
    edge_msg_sorted<<<eblocks32, 256, 0, stream>>>(h1b, eattrs, srcs, dsts,
                                                   aW1b, ab1, agg, E);
    node_update_mfma<<<nblocks, 256, 0, stream>>>(agg, h1b, mW1b, mb1, xb_h2b, 1);

    // ---- link predictor head: dense he stream + GEMM/softmax ----
    he_write_kernel<<<4096, 256, 0, stream>>>(xb_h2b, ei, flag, out_he, E);
    edge_head_mfma<<<eblocks16, 256, 0, stream>>>(xb_h2b, ei, flag, lpW1b, lpb1, lpW2, lpb2,
                                                  out_y, E);
}

// Round 14
// 568.164 us; speedup vs baseline: 1.1090x; 1.1090x over previous
//
#include <hip/hip_runtime.h>
#include <math.h>

#define NNODES 50000
#define DIM 128
#define DEDGE 64

typedef __attribute__((ext_vector_type(8))) short bf16x8;
typedef __attribute__((ext_vector_type(4))) float f32x4;
typedef __attribute__((ext_vector_type(2))) float f32x2;

__device__ __forceinline__ float bf_lo(unsigned u) { return __builtin_bit_cast(float, u << 16); }
__device__ __forceinline__ float bf_hi(unsigned u) { return __builtin_bit_cast(float, u & 0xFFFF0000u); }
__device__ __forceinline__ float bf_s(short s) {
    return __builtin_bit_cast(float, ((unsigned)(unsigned short)s) << 16);
}
__device__ __forceinline__ unsigned short f2b_rtn(float f) {
    unsigned u = __builtin_bit_cast(unsigned, f);
    u += 0x7FFFu + ((u >> 16) & 1u);
    return (unsigned short)(u >> 16);
}

// ---------------------------------------------------------------------------
// edge_index dtype detection (int64 per reference vs int32 per harness doc)
// ---------------------------------------------------------------------------
__global__ void detect_mode_kernel(const void* __restrict__ ei, int* __restrict__ flag) {
    __shared__ int bad;
    if (threadIdx.x == 0) bad = 0;
    __syncthreads();
    const long long* p = (const long long*)ei;
    int localbad = 0;
    for (int i = threadIdx.x; i < 4096; i += blockDim.x) {
        long long v = p[i];
        if (v < 0 || v >= NNODES) localbad = 1;
    }
    if (localbad) atomicOr(&bad, 1);
    __syncthreads();
    if (threadIdx.x == 0) *flag = bad ? 0 : 1;   // 1 = int64 mode
}

__device__ __forceinline__ int load_idx(const void* ei, long long pos, int mode64) {
    if (mode64) return (int)((const long long*)ei)[pos];
    return ((const int*)ei)[pos];
}

// ---------------------------------------------------------------------------
// prep: weights -> FRAGMENT-ORDER single-bf16 tables; (1+eps) folded exactly
// into the h-half (k>=128) of the GIN weights.
// layout (shorts): aW0@0 aW1@8192 mW0@16384 mW1@49152 lpW1@81920  (98304 total)
// ---------------------------------------------------------------------------
__global__ void prep_weights(const float* __restrict__ aW0, const float* __restrict__ aW1,
                             const float* __restrict__ mW0, const float* __restrict__ mW1,
                             const float* __restrict__ lpW1,
                             const float* __restrict__ eps0p, const float* __restrict__ eps1p,
                             short* __restrict__ wt)
{
    int i = blockIdx.x * 256 + threadIdx.x;   // 0..98303 (384 blocks)
    const float* src; int K, off, f;
    float scale_hi = 1.0f;   // applied to k>=128 rows (GIN h-half)
    if (i < 8192)        { src = aW0;  K = 64;  off = 0;     f = i; }
    else if (i < 16384)  { src = aW1;  K = 64;  off = 8192;  f = i - 8192; }
    else if (i < 49152)  { src = mW0;  K = 256; off = 16384; f = i - 16384;
                           scale_hi = 1.0f + eps0p[0]; }
    else if (i < 81920)  { src = mW1;  K = 256; off = 49152; f = i - 49152;
                           scale_hi = 1.0f + eps1p[0]; }
    else                 { src = lpW1; K = 128; off = 81920; f = i - 81920; }
    const int NKC = K >> 5;
    int j = f & 7, l = (f >> 3) & 63, c = f >> 9;
    int kc = c % NKC, n = c / NKC;
    int col = n * 16 + (l & 15);
    int k = kc * 32 + ((l >> 4) << 3) + j;
    float v = src[k * DIM + col];
    if (k >= 128) v *= scale_hi;
    wt[off + f] = (short)f2b_rtn(v);
}

// f32 -> bf16 table conversion (coalesced, 8 elems/thread)
__global__ void f32_to_bf16_kernel(const float* __restrict__ in,
                                   unsigned short* __restrict__ out, long long n)
{
    long long i = ((long long)blockIdx.x * 256 + threadIdx.x) * 8;
    if (i >= n) return;
    f32x4 a = *(const f32x4*)(in + i);
    f32x4 b = *(const f32x4*)(in + i + 4);
    unsigned short v[8];
#pragma unroll
    for (int t = 0; t < 4; t++) { v[t] = f2b_rtn(a[t]); v[4 + t] = f2b_rtn(b[t]); }
    unsigned p0 = v[0] | ((unsigned)v[1] << 16);
    unsigned p1 = v[2] | ((unsigned)v[3] << 16);
    unsigned p2 = v[4] | ((unsigned)v[5] << 16);
    unsigned p3 = v[6] | ((unsigned)v[7] << 16);
    f32x4 pk = {__builtin_bit_cast(float, p0), __builtin_bit_cast(float, p1),
                __builtin_bit_cast(float, p2), __builtin_bit_cast(float, p3)};
    *(f32x4*)(out + i) = pk;
}

// ---------------------------------------------------------------------------
// CSR build: histogram of dst; fast 3-pass exclusive scan; scatter.
// ---------------------------------------------------------------------------
__global__ void hist_kernel(const void* __restrict__ ei, const int* __restrict__ modep,
                            int* __restrict__ counts, int E)
{
    const int mode64 = *modep;
    for (int e = blockIdx.x * 256 + threadIdx.x; e < E; e += gridDim.x * 256)
        atomicAdd(&counts[load_idx(ei, (long long)E + e, mode64)], 1);
}

__global__ __launch_bounds__(1024) void scan1_kernel(const int* __restrict__ counts,
                                                     int* __restrict__ cursor,
                                                     int* __restrict__ bsums)
{
    __shared__ int part[1024];
    const int t = threadIdx.x;
    const int i = blockIdx.x * 1024 + t;
    int v = (i < NNODES) ? counts[i] : 0;
    part[t] = v;
    __syncthreads();
    for (int d = 1; d < 1024; d <<= 1) {
        int u = (t >= d) ? part[t - d] : 0;
        __syncthreads();
        part[t] += u;
        __syncthreads();
    }
    if (i < NNODES) cursor[i] = part[t] - v;   // exclusive within block
    if (t == 1023) bsums[blockIdx.x] = part[1023];
}

__global__ void scan2_kernel(int* __restrict__ bsums, int nb)
{
    if (threadIdx.x == 0 && blockIdx.x == 0) {
        int run = 0;
        for (int b = 0; b < nb; b++) { int c = bsums[b]; bsums[b] = run; run += c; }
    }
}

__global__ __launch_bounds__(1024) void scan3_kernel(int* __restrict__ cursor,
                                                     const int* __restrict__ bsums)
{
    const int i = blockIdx.x * 1024 + threadIdx.x;
    if (i < NNODES) cursor[i] += bsums[blockIdx.x];
}

__global__ void scatter_kernel(const void* __restrict__ ei, const int* __restrict__ modep,
                               int* __restrict__ cursor, int* __restrict__ perm,
                               int* __restrict__ srcs, int* __restrict__ dsts, int E)
{
    const int mode64 = *modep;
    for (int e = blockIdx.x * 256 + threadIdx.x; e < E; e += gridDim.x * 256) {
        int d = load_idx(ei, (long long)E + e, mode64);
        int s = load_idx(ei, e, mode64);
        int pos = atomicAdd(&cursor[d], 1);
        perm[pos] = e;
        srcs[pos] = s;
        dsts[pos] = d;
    }
}

// ---------------------------------------------------------------------------
// eattr -> bf16, permuted into dst-sorted order (linear reads downstream)
// ---------------------------------------------------------------------------
__global__ void eattr_sort_bf16(const float* __restrict__ eattr, const int* __restrict__ perm,
                                unsigned short* __restrict__ out, int E)
{
    long long i = ((long long)blockIdx.x * 256 + threadIdx.x) * 8;
    if (i >= (long long)E * DEDGE) return;
    long long pos = i >> 6;
    int k = (int)(i & 63);
    long long eid = perm[pos];
    f32x4 a = *(const f32x4*)(eattr + eid * DEDGE + k);
    f32x4 b = *(const f32x4*)(eattr + eid * DEDGE + k + 4);
    unsigned short v[8];
#pragma unroll
    for (int t = 0; t < 4; t++) { v[t] = f2b_rtn(a[t]); v[4 + t] = f2b_rtn(b[t]); }
    unsigned p0 = v[0] | ((unsigned)v[1] << 16);
    unsigned p1 = v[2] | ((unsigned)v[3] << 16);
    unsigned p2 = v[4] | ((unsigned)v[5] << 16);
    unsigned p3 = v[6] | ((unsigned)v[7] << 16);
    f32x4 pk = {__builtin_bit_cast(float, p0), __builtin_bit_cast(float, p1),
                __builtin_bit_cast(float, p2), __builtin_bit_cast(float, p3)};
    __builtin_nontemporal_store(pk, (f32x4*)(out + i));
}

// ---------------------------------------------------------------------------
// edge message + scatter over dst-SORTED edges, 2 sub-tiles (32 edges) / wave:
//   agg[dst] += relu(h[src] + eattr@W + b)
// LDS buffer reused across sub-tiles; segmented sum carried across the
// boundary; scalar atomics only at run boundaries.
// ---------------------------------------------------------------------------
__global__ __launch_bounds__(256, 4) void edge_msg_sorted(
    const unsigned short* __restrict__ hb, const unsigned short* __restrict__ eattrs,
    const int* __restrict__ srcs, const int* __restrict__ dsts,
    const short* __restrict__ Wb,
    const float* __restrict__ bvec, float* __restrict__ agg, int E)
{
    __shared__ float e_lds[4][16][132];
    const int lane = threadIdx.x & 63;
    const int w = threadIdx.x >> 6;
    const int lg = lane >> 4, lr = lane & 15;
    const long long p0 = ((long long)blockIdx.x * 4 + w) * 32;
    if (p0 >= E) return;

    float bias[8];
#pragma unroll
    for (int n = 0; n < 8; n++) bias[n] = bvec[n * 16 + lr];

    float a0 = 0.f, a1 = 0.f;
    int prev = -1;
    const bool fullwave = (p0 + 32 <= E);

#pragma unroll
    for (int st = 0; st < 2; st++) {
        const long long t0 = p0 + st * 16;
        if (t0 >= E) break;
        const long long pos = (t0 + lr < E) ? (t0 + lr) : (E - 1);
        const int sidx = srcs[pos];
        const int didx = dsts[pos];

        f32x4 acc[8];
#pragma unroll
        for (int n = 0; n < 8; n++) {
            float b = bias[n];
            acc[n] = (f32x4){b, b, b, b};
        }
        bf16x8 a[2];
#pragma unroll
        for (int kc = 0; kc < 2; kc++)
            a[kc] = __builtin_nontemporal_load(
                (const bf16x8*)(eattrs + pos * DEDGE + kc * 32 + lg * 8));

#pragma unroll
        for (int n = 0; n < 8; n++) {
#pragma unroll
            for (int kc = 0; kc < 2; kc++) {
                bf16x8 bh = *(const bf16x8*)(Wb + ((n * 2 + kc) * 64 + lane) * 8);
                acc[n] = __builtin_amdgcn_mfma_f32_16x16x32_bf16(a[kc], bh, acc[n], 0, 0, 0);
            }
        }
        // D layout: col = n*16+lr, row = lg*4+r
#pragma unroll
        for (int n = 0; n < 8; n++)
#pragma unroll
            for (int r = 0; r < 4; r++)
                e_lds[w][lg * 4 + r][n * 16 + lr] = acc[n][r];

        if (fullwave) {
            unsigned gu[16];
            int dvs[16];
#pragma unroll
            for (int r = 0; r < 16; r++) {
                int si = __shfl(sidx, r);
                gu[r] = *(const unsigned*)&hb[(long long)si * DIM + 2 * lane];
            }
#pragma unroll
            for (int r = 0; r < 16; r++) dvs[r] = __shfl(didx, r);
#pragma unroll
            for (int r = 0; r < 16; r++) {
                f32x2 ev = *(const f32x2*)&e_lds[w][r][2 * lane];
                float m0 = fmaxf(ev.x + bf_lo(gu[r]), 0.f);
                float m1 = fmaxf(ev.y + bf_hi(gu[r]), 0.f);
                if (dvs[r] != prev && prev >= 0) {
                    float* d = &agg[(long long)prev * DIM + 2 * lane];
                    unsafeAtomicAdd(d, a0);
                    unsafeAtomicAdd(d + 1, a1);
                    a0 = 0.f; a1 = 0.f;
                }
                a0 += m0; a1 += m1; prev = dvs[r];
            }
        } else {
            for (int r = 0; r < 16; r++) {
                if (t0 + r >= E) break;
                int di = __shfl(didx, r);
                int si = __shfl(sidx, r);
                f32x2 ev = *(const f32x2*)&e_lds[w][r][2 * lane];
                unsigned u = *(const unsigned*)&hb[(long long)si * DIM + 2 * lane];
                float m0 = fmaxf(ev.x + bf_lo(u), 0.f);
                float m1 = fmaxf(ev.y + bf_hi(u), 0.f);
                if (di != prev && prev >= 0) {
                    float* d = &agg[(long long)prev * DIM + 2 * lane];
                    unsafeAtomicAdd(d, a0);
                    unsafeAtomicAdd(d + 1, a1);
                    a0 = 0.f; a1 = 0.f;
                }
                a0 += m0; a1 += m1; prev = di;
            }
        }
    }
    if (prev >= 0) {
        float* d = &agg[(long long)prev * DIM + 2 * lane];
        unsafeAtomicAdd(d, a0);
        unsafeAtomicAdd(d + 1, a1);
    }
}

// ---------------------------------------------------------------------------
// GIN update: houtb = bf16(act([agg | (1+eps)*h] @ W + b)); eps pre-folded.
// agg streamed non-temporally (one-shot), h already bf16. 64 MFMA.
// ---------------------------------------------------------------------------
__global__ __launch_bounds__(256, 4) void node_update_mfma(
    const float* __restrict__ agg, const unsigned short* __restrict__ hb,
    const short* __restrict__ Wb, const float* __restrict__ bvec,
    unsigned short* __restrict__ houtb, int relu_flag)
{
    __shared__ float st[4][16][132];
    const int lane = threadIdx.x & 63;
    const int w = threadIdx.x >> 6;
    const int lg = lane >> 4, lr = lane & 15;
    const int n0 = (blockIdx.x * 4 + w) * 16;
    if (n0 >= NNODES) return;
    const int arow = (n0 + lr < NNODES) ? (n0 + lr) : (NNODES - 1);

    f32x4 acc[8];
#pragma unroll
    for (int n = 0; n < 8; n++) {
        float b = bvec[n * 16 + lr];
        acc[n] = (f32x4){b, b, b, b};
    }
#pragma unroll
    for (int kc = 0; kc < 8; kc++) {
        bf16x8 av;
        if (kc < 4) {
            const int k = kc * 32 + lg * 8;
            f32x4 v0 = __builtin_nontemporal_load((const f32x4*)(agg + (long long)arow * DIM + k));
            f32x4 v1 = __builtin_nontemporal_load((const f32x4*)(agg + (long long)arow * DIM + k + 4));
#pragma unroll
            for (int i = 0; i < 4; i++) {
                av[i] = (short)f2b_rtn(v0[i]);
                av[4 + i] = (short)f2b_rtn(v1[i]);
            }
        } else {
            av = *(const bf16x8*)(hb + (long long)arow * DIM + (kc - 4) * 32 + lg * 8);
        }
#pragma unroll
        for (int n = 0; n < 8; n++) {
            bf16x8 bh = *(const bf16x8*)(Wb + ((n * 8 + kc) * 64 + lane) * 8);
            acc[n] = __builtin_amdgcn_mfma_f32_16x16x32_bf16(av, bh, acc[n], 0, 0, 0);
        }
    }
#pragma unroll
    for (int n = 0; n < 8; n++) {
#pragma unroll
        for (int r = 0; r < 4; r++) {
            float z = acc[n][r];
            z = relu_flag ? fmaxf(z, 0.f) : (z > 0.f ? z : 0.2f * z);
            st[w][lg * 4 + r][n * 16 + lr] = z;
        }
    }
    for (int r = 0; r < 16; r++) {
        int row = n0 + r;
        if (row >= NNODES) break;
        f32x2 v = *(const f32x2*)&st[w][r][2 * lane];
        unsigned pk = (unsigned)f2b_rtn(v.x) | ((unsigned)f2b_rtn(v.y) << 16);
        *(unsigned*)&houtb[(long long)row * DIM + 2 * lane] = pk;
    }
}

// ---------------------------------------------------------------------------
// edge head (round-12 form — measured optimum, 569 µs total):
// he = h[src]*h[dst] (exact f32 product of bf16), nt-write f32;
// z = leaky(he@W1+b1), 32 MFMA; yhat = softmax2, coalesced 128B store/tile.
// LOCKED: 1 tile/wave + 6 waves/SIMD + fused he-write. Alternatives measured
// worse: 8 waves (r11 +53us), 2 tiles/wave (r10 +166us), split he stream
// (r13 +61us), sort-based dataflow (r9 +103us).
// ---------------------------------------------------------------------------
__global__ __launch_bounds__(256, 6) void edge_head_mfma(
    const unsigned short* __restrict__ hb, const void* __restrict__ ei,
    const int* __restrict__ modep,
    const short* __restrict__ W1b, const float* __restrict__ b1,
    const float* __restrict__ W2, const float* __restrict__ b2,
    float* __restrict__ out_he, float* __restrict__ out_y, int E)
{
    const int mode64 = *modep;
    const int lane = threadIdx.x & 63;
    const int w = threadIdx.x >> 6;
    const int lg = lane >> 4, lr = lane & 15;
    const long long e0 = ((long long)blockIdx.x * 4 + w) * 16;
    if (e0 >= E) return;
    const bool full = (e0 + 16 <= E);
    const long long erow = (full || e0 + lr < E) ? (e0 + lr) : (E - 1);
    int si = load_idx(ei, erow, mode64);
    int di = load_idx(ei, (long long)E + erow, mode64);

    f32x4 acc[8];
#pragma unroll
    for (int n = 0; n < 8; n++) {
        float b = b1[n * 16 + lr];
        acc[n] = (f32x4){b, b, b, b};
    }
    bf16x8 ab[4];
#pragma unroll
    for (int kc = 0; kc < 4; kc++) {
        const int k = kc * 32 + lg * 8;
        bf16x8 hs = *(const bf16x8*)(hb + (long long)si * DIM + k);
        bf16x8 hd = *(const bf16x8*)(hb + (long long)di * DIM + k);
        f32x4 p0, p1;
#pragma unroll
        for (int i = 0; i < 4; i++) {
            p0[i] = bf_s(hs[i]) * bf_s(hd[i]);
            p1[i] = bf_s(hs[4 + i]) * bf_s(hd[4 + i]);
        }
        if (full || e0 + lr < E) {
            __builtin_nontemporal_store(p0, (f32x4*)(out_he + erow * DIM + k));
            __builtin_nontemporal_store(p1, (f32x4*)(out_he + erow * DIM + k + 4));
        }
#pragma unroll
        for (int i = 0; i < 4; i++) {
            ab[kc][i] = (short)f2b_rtn(p0[i]);
            ab[kc][4 + i] = (short)f2b_rtn(p1[i]);
        }
    }
#pragma unroll
    for (int n = 0; n < 8; n++) {
#pragma unroll
        for (int kc = 0; kc < 4; kc++) {
            bf16x8 bh = *(const bf16x8*)(W1b + ((n * 4 + kc) * 64 + lane) * 8);
            acc[n] = __builtin_amdgcn_mfma_f32_16x16x32_bf16(ab[kc], bh, acc[n], 0, 0, 0);
        }
    }
    float q0[4] = {0.f, 0.f, 0.f, 0.f}, q1[4] = {0.f, 0.f, 0.f, 0.f};
#pragma unroll
    for (int n = 0; n < 8; n++) {
        float w2a = W2[(n * 16 + lr) * 2 + 0];
        float w2b = W2[(n * 16 + lr) * 2 + 1];
#pragma unroll
        for (int r = 0; r < 4; r++) {
            float z = acc[n][r];
            z = z > 0.f ? z : 0.2f * z;
            q0[r] = fmaf(z, w2a, q0[r]);
            q1[r] = fmaf(z, w2b, q1[r]);
        }
    }
#pragma unroll
    for (int m = 1; m < 16; m <<= 1) {
#pragma unroll
        for (int r = 0; r < 4; r++) {
            q0[r] += __shfl_xor(q0[r], m);
            q1[r] += __shfl_xor(q1[r], m);
        }
    }
    float c0 = b2[0], c1 = b2[1];
    float s0[4], s1[4];
#pragma unroll
    for (int r = 0; r < 4; r++) {
        float l0 = q0[r] + c0, l1 = q1[r] + c1;
        float mx = fmaxf(l0, l1);
        float x0 = expf(l0 - mx), x1 = expf(l1 - mx);
        float inv = 1.f / (x0 + x1);
        s0[r] = x0 * inv;
        s1[r] = x1 * inv;
    }
    if (full) {
        float ea = (lane & 2) ? s0[1] : s0[0];
        float eb = (lane & 2) ? s0[3] : s0[2];
        float ec = (lane & 2) ? s1[1] : s1[0];
        float ed = (lane & 2) ? s1[3] : s1[2];
        float e0v = (lane & 4) ? eb : ea;
        float e1v = (lane & 4) ? ed : ec;
        float ex = (lane & 1) ? e1v : e0v;
        float v = __shfl(ex, ((lane >> 3) << 4) + (lane & 7));
        if (lane < 32)
            __builtin_nontemporal_store(v, &out_y[e0 * 2 + lane]);
    } else if (lr == 0) {
#pragma unroll
        for (int r = 0; r < 4; r++) {
            long long e = e0 + lg * 4 + r;
            if (e < E) {
                out_y[e * 2 + 0] = s0[r];
                out_y[e * 2 + 1] = s1[r];
            }
        }
    }
}

extern "C" void kernel_launch(void* const* d_in, const int* in_sizes, int n_in,
                              void* d_out, int out_size, void* d_ws, size_t ws_size,
                              hipStream_t stream)
{
    const float* x     = (const float*)d_in[0];
    const void*  ei    = d_in[1];
    const float* eattr = (const float*)d_in[2];
    const float* aW0   = (const float*)d_in[3];
    const float* ab0   = (const float*)d_in[4];
    const float* mW0   = (const float*)d_in[5];
    const float* mb0   = (const float*)d_in[6];
    const float* eps0  = (const float*)d_in[7];
    const float* aW1   = (const float*)d_in[8];
    const float* ab1   = (const float*)d_in[9];
    const float* mW1   = (const float*)d_in[10];
    const float* mb1   = (const float*)d_in[11];
    const float* eps1  = (const float*)d_in[12];
    const float* lpW1  = (const float*)d_in[13];
    const float* lpb1  = (const float*)d_in[14];
    const float* lpW2  = (const float*)d_in[15];
    const float* lpb2  = (const float*)d_in[16];

    const int E = in_sizes[1] / 2;
    const long long NTAB = (long long)NNODES * DIM;   // 6.4M

    float* wsf  = (float*)d_ws;
    int*   flag = (int*)d_ws;
    float* agg  = wsf + 64;
    short* wt   = (short*)(agg + NTAB);
    unsigned short* xb_h2b = (unsigned short*)(wt + 98304); // x bf16, later h2 bf16
    unsigned short* h1b    = xb_h2b + NTAB;
    int* counts = (int*)(h1b + NTAB);
    int* cursor = counts + 50048;
    int* bsums  = cursor + 50048;            // 64 used
    int* perm   = bsums + 64;
    int* srcs   = perm + E;
    int* dsts   = srcs + E;
    unsigned short* eattrs = (unsigned short*)(dsts + E);  // sorted bf16 eattr

    float* out_he = (float*)d_out;
    float* out_y  = out_he + (long long)E * DIM;

    const short* aW0b  = wt;
    const short* aW1b  = wt + 8192;
    const short* mW0b  = wt + 16384;
    const short* mW1b  = wt + 49152;
    const short* lpW1b = wt + 81920;

    detect_mode_kernel<<<1, 256, 0, stream>>>(ei, flag);
    prep_weights<<<384, 256, 0, stream>>>(aW0, aW1, mW0, mW1, lpW1, eps0, eps1, wt);
    f32_to_bf16_kernel<<<(int)(NTAB / 8 / 256), 256, 0, stream>>>(x, xb_h2b, NTAB);

    // ---- CSR build (edge structure is layer-invariant) ----
    hipMemsetAsync(counts, 0, 50048 * sizeof(int), stream);
    hist_kernel<<<1024, 256, 0, stream>>>(ei, flag, counts, E);
    const int sblocks = (NNODES + 1023) / 1024;   // 49
    scan1_kernel<<<sblocks, 1024, 0, stream>>>(counts, cursor, bsums);
    scan2_kernel<<<1, 64, 0, stream>>>(bsums, sblocks);
    scan3_kernel<<<sblocks, 1024, 0, stream>>>(cursor, bsums);
    scatter_kernel<<<1024, 256, 0, stream>>>(ei, flag, cursor, perm, srcs, dsts, E);
    eattr_sort_bf16<<<(E * DEDGE / 8 + 255) / 256, 256, 0, stream>>>(eattr, perm, eattrs, E);

    const int eblocks32 = (E + 127) / 128;   // 32 edges per wave, 4 waves/block
    const int eblocks16 = (E + 63) / 64;     // 16 edges per wave
    const int nblocks = (NNODES + 63) / 64;

    // ---- layer 0 ----
    hipMemsetAsync(agg, 0, NTAB * sizeof(float), stream);
    edge_msg_sorted<<<eblocks32, 256, 0, stream>>>(xb_h2b, eattrs, srcs, dsts,
                                                   aW0b, ab0, agg, E);
    node_update_mfma<<<nblocks, 256, 0, stream>>>(agg, xb_h2b, mW0b, mb0, h1b, 0);

    // ---- layer 1 ----
    hipMemsetAsync(agg, 0, NTAB * sizeof(float), stream);
    edge_msg_sorted<<<eblocks32, 256, 0, stream>>>(h1b, eattrs, srcs, dsts,
                                                   aW1b, ab1, agg, E);
    node_update_mfma<<<nblocks, 256, 0, stream>>>(agg, h1b, mW1b, mb1, xb_h2b, 1);

    // ---- link predictor head ----
    edge_head_mfma<<<eblocks16, 256, 0, stream>>>(xb_h2b, ei, flag, lpW1b, lpb1, lpW2, lpb2,
                                                  out_he, out_y, E);
}